// Round 4
// baseline (904.606 us; speedup 1.0000x reference)
//
#include <hip/hip_runtime.h>
#include <hip/hip_fp16.h>

// ---------------------------------------------------------------------------
// NodeModelLtp: edge MLP (Linear(256->128)+ReLU, Linear(128->128), LN) ->
// scatter-mean over dst -> node MLP (Linear(384->128)+ReLU, Linear(128->128), LN)
// bf16 MFMA (16x16x32) with fp32 accumulate; weights register-resident.
//
// R4 changes vs R3 (796 us):
//  - 512-thread / 8-wave blocks, each wave owns a 16-col n-slice (was 4 waves
//    x 32 cols). Halves per-thread weight VGPRs (96->48) and live AGPR accs
//    (32->16). Total regs ~120 -> __launch_bounds__(512,4) => 16 waves/CU
//    (2 blocks/CU), double R3's 8 waves/CU. Occupancy was the binding limit
//    (VGPR+AGPR ~192 -> 2 old blocks/CU); LDS (52KB x 2) and grid now fit.
//  - Same dataflow, barriers, f16 pk atomics, separate h1s (no aliasing).
// ---------------------------------------------------------------------------

typedef __bf16 bf16x8 __attribute__((ext_vector_type(8)));
typedef float floatx4 __attribute__((ext_vector_type(4)));

__device__ __forceinline__ unsigned short f2bf(float f) {
    unsigned int u = __float_as_uint(f);
    u = u + 0x7FFFu + ((u >> 16) & 1u);   // RNE
    return (unsigned short)(u >> 16);
}
__device__ __forceinline__ unsigned int pk2(float a, float b) {
    return (unsigned int)f2bf(a) | ((unsigned int)f2bf(b) << 16);
}

// --- detect whether edge_idx buffer is int64 (odd 32-bit words all zero) ----
__global__ void detect_idx64(const unsigned int* __restrict__ idx, int* __restrict__ flag) {
    if (threadIdx.x == 0 && blockIdx.x == 0) {
        unsigned int o = 0;
        for (int i = 1; i < 64; i += 2) o |= idx[i];
        *flag = (o == 0u) ? 1 : 0;
    }
}

// --- convert + transpose weights to bf16 [n][K] -----------------------------
__global__ void prep_weights(const float* __restrict__ W1a, const float* __restrict__ W2a,
                             const float* __restrict__ W1b, const float* __restrict__ W2b,
                             unsigned short* __restrict__ w1aT, unsigned short* __restrict__ w2aT,
                             unsigned short* __restrict__ w1bT, unsigned short* __restrict__ w2bT) {
    int g = blockIdx.x * 256 + threadIdx.x;
    if (g < 32768) {                       // W1aT [128][256]
        int n = g >> 8, k = g & 255;
        w1aT[g] = f2bf(W1a[k * 128 + n]);
    } else if (g < 49152) {                // W2aT [128][128]
        int l = g - 32768; int n = l >> 7, k = l & 127;
        w2aT[l] = f2bf(W2a[k * 128 + n]);
    } else if (g < 98304) {                // W1bT [128][384]
        int l = g - 49152; int n = l / 384, k = l - n * 384;
        w1bT[l] = f2bf(W1b[k * 128 + n]);
    } else if (g < 114688) {               // W2bT [128][128]
        int l = g - 98304; int n = l >> 7, k = l & 127;
        w2bT[l] = f2bf(W2b[k * 128 + n]);
    }
}

// --- edge MLP + LayerNorm + atomic scatter ----------------------------------
__global__ __launch_bounds__(512, 4) void edge_mlp_scatter(
    const float* __restrict__ x, const void* __restrict__ eidx,
    const float* __restrict__ ea,
    const float* __restrict__ b1a, const float* __restrict__ b2a,
    const float* __restrict__ g1, const float* __restrict__ be1,
    const unsigned short* __restrict__ w1aT, const unsigned short* __restrict__ w2aT,
    float* __restrict__ summed, __half* __restrict__ summedH,
    float* __restrict__ counts,
    const int* __restrict__ flag64, int E, int useHalf)
{
    __shared__ union {
        unsigned short msg[64 * 264];   // 64 edges x (256 + 8 pad) bf16  = 33792 B
        float h2[64 * 132];             // 64 x (128 + 4 pad) fp32        = 33792 B
    } uA;
    __shared__ unsigned short h1s[64 * 136];  // 17408 B
    __shared__ int lsRow[64], lsCol[64];
    __shared__ float sMean[64], sRstd[64];

    const int tid  = threadIdx.x;
    const int lane = tid & 63;
    const int wave = tid >> 6;          // 0..7
    const int quad = lane >> 4;
    const int lm   = lane & 15;
    const int ns   = wave * 16;         // this wave's 16-col n-slice

    // register-resident weight fragments (B-layout: [n=lane&15][k=quad*8+j])
    bf16x8 wf1[8], wf2[4];
#pragma unroll
    for (int kk = 0; kk < 8; kk++)
        wf1[kk] = *(const bf16x8*)(w1aT + (ns + lm) * 256 + kk * 32 + quad * 8);
#pragma unroll
    for (int kk = 0; kk < 4; kk++)
        wf2[kk] = *(const bf16x8*)(w2aT + (ns + lm) * 128 + kk * 32 + quad * 8);

    const float b1v = b1a[ns + lm];
    const float b2v = b2a[ns + lm];
    // fp32-path epilogue params (one col per thread over 128)
    const int colT = tid & 127;
    const float gv = g1[colT], bev = be1[colT];
    // f16-path epilogue params (col pair per thread over 64 pairs)
    const int colP = tid & 63;
    float gA = 0.f, gB = 0.f, bA = 0.f, bB = 0.f;
    if (useHalf) {
        gA = g1[colP * 2];  gB = g1[colP * 2 + 1];
        bA = be1[colP * 2]; bB = be1[colP * 2 + 1];
    }
    const int use64 = *flag64;

    const int numTiles = (E + 63) >> 6;
    for (int t = blockIdx.x; t < numTiles; t += gridDim.x) {
        const int eb = t << 6;
        __syncthreads();  // B1: prev tile's scatter readers (h2 + lsRow) done
        if (tid < 64) {
            int e = eb + tid; if (e >= E) e = E - 1;
            int r, c;
            if (use64) { const long long* p = (const long long*)eidx; r = (int)p[e]; c = (int)p[E + e]; }
            else       { const int* p = (const int*)eidx;             r = p[e];      c = p[E + e]; }
            lsRow[tid] = r; lsCol[tid] = c;
        }
        __syncthreads();  // B2: indices ready
        // ---- stage msg = [x[col] | edge_attr] as bf16 (512 threads) ----
        {
            const int rl = tid >> 5, l32 = tid & 31;   // rl: 0..15
#pragma unroll
            for (int it = 0; it < 4; it++) {
                const int e = it * 16 + rl;
                int eg = eb + e; if (eg >= E) eg = E - 1;
                const float4 xv = ((const float4*)(x + (size_t)lsCol[e] * 128))[l32];
                const float4 av = ((const float4*)(ea + (size_t)eg * 128))[l32];
                *(unsigned int*)&uA.msg[e * 264 + l32 * 4]           = pk2(xv.x, xv.y);
                *(unsigned int*)&uA.msg[e * 264 + l32 * 4 + 2]       = pk2(xv.z, xv.w);
                *(unsigned int*)&uA.msg[e * 264 + 128 + l32 * 4]     = pk2(av.x, av.y);
                *(unsigned int*)&uA.msg[e * 264 + 128 + l32 * 4 + 2] = pk2(av.z, av.w);
            }
        }
        __syncthreads();  // B3: msg ready
        // ---- layer 1: [64x256] @ [256x128], wave covers 16 cols ----
        floatx4 acc1[4] = {};
#pragma unroll
        for (int mt = 0; mt < 4; mt++)
#pragma unroll
            for (int kk = 0; kk < 8; kk++) {
                bf16x8 a = *(const bf16x8*)&uA.msg[(mt * 16 + lm) * 264 + kk * 32 + quad * 8];
                acc1[mt] = __builtin_amdgcn_mfma_f32_16x16x32_bf16(a, wf1[kk], acc1[mt], 0, 0, 0);
            }
        // bias + relu -> h1 (bf16, separate buffer)
#pragma unroll
        for (int mt = 0; mt < 4; mt++)
#pragma unroll
            for (int r = 0; r < 4; r++) {
                const int row = mt * 16 + quad * 4 + r;
                h1s[row * 136 + ns + lm] = f2bf(fmaxf(acc1[mt][r] + b1v, 0.f));
            }
        __syncthreads();  // B4: h1 ready (and all msg reads done)
        // ---- layer 2: [64x128] @ [128x128] ----
        floatx4 acc2[4] = {};
#pragma unroll
        for (int mt = 0; mt < 4; mt++)
#pragma unroll
            for (int kk = 0; kk < 4; kk++) {
                bf16x8 a = *(const bf16x8*)&h1s[(mt * 16 + lm) * 136 + kk * 32 + quad * 8];
                acc2[mt] = __builtin_amdgcn_mfma_f32_16x16x32_bf16(a, wf2[kk], acc2[mt], 0, 0, 0);
            }
        // + bias -> h2 fp32 (reuses msg area; msg readers done at B4)
#pragma unroll
        for (int mt = 0; mt < 4; mt++)
#pragma unroll
            for (int r = 0; r < 4; r++) {
                const int row = mt * 16 + quad * 4 + r;
                uA.h2[row * 132 + ns + lm] = acc2[mt][r] + b2v;
            }
        __syncthreads();  // B5: h2 ready
        // ---- LayerNorm stats: 8 threads per edge (+ counts atomic) ----
        {
            const int e = tid >> 3, q = tid & 7;
            const float4* hp = (const float4*)&uA.h2[e * 132 + q * 16];
            float s = 0.f, ss = 0.f;
#pragma unroll
            for (int i = 0; i < 4; i++) {
                float4 v = hp[i];
                s  += v.x + v.y + v.z + v.w;
                ss += v.x * v.x + v.y * v.y + v.z * v.z + v.w * v.w;
            }
            s  += __shfl_xor(s, 1);  s  += __shfl_xor(s, 2);  s  += __shfl_xor(s, 4);
            ss += __shfl_xor(ss, 1); ss += __shfl_xor(ss, 2); ss += __shfl_xor(ss, 4);
            if (q == 0) {
                float mean = s * (1.f / 128.f);
                float var  = ss * (1.f / 128.f) - mean * mean;
                sMean[e] = mean;
                sRstd[e] = rsqrtf(var + 1e-5f);
                if (eb + e < E) unsafeAtomicAdd(counts + lsRow[e], 1.f);
            }
        }
        __syncthreads();  // B6: stats ready
        // ---- normalized scatter-add ----
        if (useHalf) {
            // packed f16 atomics: wave w handles edges {it*8+w}
#pragma unroll
            for (int it = 0; it < 8; it++) {
                const int e = it * 8 + wave;
                if (eb + e < E) {
                    const float2 h = *(const float2*)&uA.h2[e * 132 + colP * 2];
                    const float m = sMean[e], rs = sRstd[e];
                    const float v0 = (h.x - m) * rs * gA + bA;
                    const float v1 = (h.y - m) * rs * gB + bB;
                    unsafeAtomicAdd((__half2*)(summedH + (size_t)lsRow[e] * 128 + colP * 2),
                                    __floats2half2_rn(v0, v1));
                }
            }
        } else {
#pragma unroll
            for (int it = 0; it < 16; it++) {
                const int e = it * 4 + (tid >> 7);
                if (eb + e < E) {
                    float v = (uA.h2[e * 132 + colT] - sMean[e]) * sRstd[e] * gv + bev;
                    unsafeAtomicAdd(summed + (size_t)lsRow[e] * 128 + colT, v);
                }
            }
        }
    }
}

// --- node MLP + LayerNorm -> out --------------------------------------------
__global__ __launch_bounds__(512, 4) void node_mlp(
    const float* __restrict__ x, const float* __restrict__ u,
    const float* summed, const __half* __restrict__ summedH,
    const float* __restrict__ counts,
    const float* __restrict__ b1b, const float* __restrict__ b2b,
    const float* __restrict__ g2, const float* __restrict__ be2,
    const unsigned short* __restrict__ w1bT, const unsigned short* __restrict__ w2bT,
    float* out, int NN, int useHalf)
{
    __shared__ union {
        unsigned short msg[32 * 392];   // 32 nodes x (384 + 8 pad) bf16 = 25088 B
        float h2[32 * 132];             // 16896 B
    } uA;
    __shared__ unsigned short h1s[32 * 136];  // 8704 B
    __shared__ float sMean[32], sRstd[32];

    const int tid  = threadIdx.x;
    const int lane = tid & 63;
    const int wave = tid >> 6;          // 0..7
    const int quad = lane >> 4;
    const int lm   = lane & 15;
    const int ns   = wave * 16;

    bf16x8 wf1[12], wf2[4];
#pragma unroll
    for (int kk = 0; kk < 12; kk++)
        wf1[kk] = *(const bf16x8*)(w1bT + (ns + lm) * 384 + kk * 32 + quad * 8);
#pragma unroll
    for (int kk = 0; kk < 4; kk++)
        wf2[kk] = *(const bf16x8*)(w2bT + (ns + lm) * 128 + kk * 32 + quad * 8);

    const float b1v = b1b[ns + lm];
    const float b2v = b2b[ns + lm];
    const int colT = tid & 127;
    const float gv = g2[colT], bev = be2[colT];

    const int numTiles = (NN + 31) >> 5;
    for (int t = blockIdx.x; t < numTiles; t += gridDim.x) {
        const int nb = t << 5;
        __syncthreads();
        // ---- stage z = [x | summed/clip(counts,1) | u] as bf16 (512 thr) ----
        {
            const int rl = tid >> 5, l32 = tid & 31;   // rl: 0..15
#pragma unroll
            for (int it = 0; it < 2; it++) {
                const int rloc = it * 16 + rl;
                int i = nb + rloc; if (i >= NN) i = NN - 1;
                const float4 xv = ((const float4*)(x + (size_t)i * 128))[l32];
                float4 sv;
                if (useHalf) {
                    const float2 rw = ((const float2*)(summedH + (size_t)i * 128))[l32];
                    const __half2 h01 = *(const __half2*)&rw.x;
                    const __half2 h23 = *(const __half2*)&rw.y;
                    const float2 a = __half22float2(h01);
                    const float2 b = __half22float2(h23);
                    sv.x = a.x; sv.y = a.y; sv.z = b.x; sv.w = b.y;
                } else {
                    sv = ((const float4*)(summed + (size_t)i * 128))[l32];
                }
                const float inv = 1.f / fmaxf(counts[i], 1.f);
                sv.x *= inv; sv.y *= inv; sv.z *= inv; sv.w *= inv;
                const float4 uv = ((const float4*)(u + (size_t)i * 128))[l32];
                *(unsigned int*)&uA.msg[rloc * 392 + l32 * 4]           = pk2(xv.x, xv.y);
                *(unsigned int*)&uA.msg[rloc * 392 + l32 * 4 + 2]       = pk2(xv.z, xv.w);
                *(unsigned int*)&uA.msg[rloc * 392 + 128 + l32 * 4]     = pk2(sv.x, sv.y);
                *(unsigned int*)&uA.msg[rloc * 392 + 128 + l32 * 4 + 2] = pk2(sv.z, sv.w);
                *(unsigned int*)&uA.msg[rloc * 392 + 256 + l32 * 4]     = pk2(uv.x, uv.y);
                *(unsigned int*)&uA.msg[rloc * 392 + 256 + l32 * 4 + 2] = pk2(uv.z, uv.w);
            }
        }
        __syncthreads();
        // ---- layer 1: [32x384] @ [384x128], wave covers 16 cols ----
        floatx4 acc1[2] = {};
#pragma unroll
        for (int mt = 0; mt < 2; mt++)
#pragma unroll
            for (int kk = 0; kk < 12; kk++) {
                bf16x8 a = *(const bf16x8*)&uA.msg[(mt * 16 + lm) * 392 + kk * 32 + quad * 8];
                acc1[mt] = __builtin_amdgcn_mfma_f32_16x16x32_bf16(a, wf1[kk], acc1[mt], 0, 0, 0);
            }
#pragma unroll
        for (int mt = 0; mt < 2; mt++)
#pragma unroll
            for (int r = 0; r < 4; r++) {
                const int row = mt * 16 + quad * 4 + r;
                h1s[row * 136 + ns + lm] = f2bf(fmaxf(acc1[mt][r] + b1v, 0.f));
            }
        __syncthreads();
        // ---- layer 2: [32x128] @ [128x128] ----
        floatx4 acc2[2] = {};
#pragma unroll
        for (int mt = 0; mt < 2; mt++)
#pragma unroll
            for (int kk = 0; kk < 4; kk++) {
                bf16x8 a = *(const bf16x8*)&h1s[(mt * 16 + lm) * 136 + kk * 32 + quad * 8];
                acc2[mt] = __builtin_amdgcn_mfma_f32_16x16x32_bf16(a, wf2[kk], acc2[mt], 0, 0, 0);
            }
#pragma unroll
        for (int mt = 0; mt < 2; mt++)
#pragma unroll
            for (int r = 0; r < 4; r++) {
                const int row = mt * 16 + quad * 4 + r;
                uA.h2[row * 132 + ns + lm] = acc2[mt][r] + b2v;
            }
        __syncthreads();
        // ---- LayerNorm stats: 16 threads per node ----
        {
            const int e = tid >> 4, q = tid & 15;
            const float4* hp = (const float4*)&uA.h2[e * 132 + q * 8];
            float s = 0.f, ss = 0.f;
#pragma unroll
            for (int i = 0; i < 2; i++) {
                float4 v = hp[i];
                s  += v.x + v.y + v.z + v.w;
                ss += v.x * v.x + v.y * v.y + v.z * v.z + v.w * v.w;
            }
            s  += __shfl_xor(s, 1);  s  += __shfl_xor(s, 2);  s  += __shfl_xor(s, 4);  s  += __shfl_xor(s, 8);
            ss += __shfl_xor(ss, 1); ss += __shfl_xor(ss, 2); ss += __shfl_xor(ss, 4); ss += __shfl_xor(ss, 8);
            if (q == 0) {
                float mean = s * (1.f / 128.f);
                float var  = ss * (1.f / 128.f) - mean * mean;
                sMean[e] = mean;
                sRstd[e] = rsqrtf(var + 1e-5f);
            }
        }
        __syncthreads();
        // ---- normalized coalesced store (512 threads) ----
        {
            const int g4 = tid >> 7;   // 0..3
#pragma unroll
            for (int it = 0; it < 8; it++) {
                const int rloc = it * 4 + g4;
                const int i = nb + rloc;
                if (i < NN) {
                    float v = (uA.h2[rloc * 132 + colT] - sMean[rloc]) * sRstd[rloc] * gv + bev;
                    out[(size_t)i * 128 + colT] = v;
                }
            }
        }
    }
}

extern "C" void kernel_launch(void* const* d_in, const int* in_sizes, int n_in,
                              void* d_out, int out_size, void* d_ws, size_t ws_size,
                              hipStream_t stream)
{
    const float* x   = (const float*)d_in[0];
    const void*  eidx = d_in[1];
    const float* ea  = (const float*)d_in[2];
    const float* u   = (const float*)d_in[3];
    const float* W1a = (const float*)d_in[4];
    const float* b1a = (const float*)d_in[5];
    const float* W2a = (const float*)d_in[6];
    const float* b2a = (const float*)d_in[7];
    const float* g1  = (const float*)d_in[8];
    const float* be1 = (const float*)d_in[9];
    const float* W1b = (const float*)d_in[10];
    const float* b1b = (const float*)d_in[11];
    const float* W2b = (const float*)d_in[12];
    const float* b2b = (const float*)d_in[13];
    const float* g2  = (const float*)d_in[14];
    const float* be2 = (const float*)d_in[15];

    const int NN = in_sizes[0] / 128;
    const int E  = in_sizes[2] / 128;

    // workspace layout: counts[N] | flag | bf16 weights | (optional) f16 summed
    float* counts = (float*)d_ws;
    int*   flag   = (int*)((char*)d_ws + (size_t)NN * 4);
    size_t woff   = (((size_t)NN * 4 + 4) + 15) & ~(size_t)15;
    unsigned short* w1aT = (unsigned short*)((char*)d_ws + woff);
    unsigned short* w2aT = w1aT + 128 * 256;
    unsigned short* w1bT = w2aT + 128 * 128;
    unsigned short* w2bT = w1bT + 128 * 384;
    size_t shoff  = (woff + (size_t)(128*256 + 128*128 + 128*384 + 128*128) * 2 + 255) & ~(size_t)255;
    __half* summedH = (__half*)((char*)d_ws + shoff);
    const int useHalf = (ws_size >= shoff + (size_t)NN * 128 * 2) ? 1 : 0;

    float* outf = (float*)d_out;   // fp32 fallback: doubles as the scatter-sum buffer

    if (useHalf) {
        hipMemsetAsync(summedH, 0, (size_t)NN * 128 * 2, stream);
    } else {
        hipMemsetAsync(d_out, 0, (size_t)out_size * 4, stream);
    }
    hipMemsetAsync(counts, 0, (size_t)NN * 4, stream);
    detect_idx64<<<1, 64, 0, stream>>>((const unsigned int*)eidx, flag);
    prep_weights<<<448, 256, 0, stream>>>(W1a, W2a, W1b, W2b, w1aT, w2aT, w1bT, w2bT);

    edge_mlp_scatter<<<512, 512, 0, stream>>>(x, eidx, ea, b1a, b2a, g1, be1,
                                              w1aT, w2aT, outf, summedH, counts, flag, E, useHalf);

    node_mlp<<<512, 512, 0, stream>>>(x, u, outf, summedH, counts, b1b, b2b, g2, be2,
                                      w1bT, w2bT, outf, NN, useHalf);
}